// Round 5
// baseline (2126.554 us; speedup 1.0000x reference)
//
#include <hip/hip_runtime.h>
#include <hip/hip_bf16.h>

#define N_NODES   100000
#define N_EDGES   1600000
#define N_GRAPHS  64
#define FDIM      128
#define N_LABELS  20
#define SCAN_BLOCKS 391   // ceil(N_NODES/256)

// ---------------- init: zero deg, pool, zrow, csr pads ----------------
__global__ __launch_bounds__(256) void init_kernel(
    int* __restrict__ deg, float* __restrict__ pool, float* __restrict__ zrow,
    int* __restrict__ csr, int* __restrict__ csr2) {
  int i = blockIdx.x * 256 + threadIdx.x;
  if (i < N_NODES) deg[i] = 0;
  if (i < N_GRAPHS * 256) pool[i] = 0.f;
  if (i < FDIM) zrow[i] = 0.f;
  if (i < 8) { csr[N_EDGES + i] = 0; csr2[N_EDGES + i] = 0; }
}

// ---------------- CSR build ----------------
__global__ void count_kernel(const int* __restrict__ ei, int* __restrict__ deg) {
  int e = blockIdx.x * 256 + threadIdx.x;
  if (e < N_EDGES) atomicAdd(&deg[ei[N_EDGES + e]], 1);
}

__global__ __launch_bounds__(256) void scan1_kernel(
    const int* __restrict__ deg, int* __restrict__ offsets,
    int* __restrict__ blockSums) {
  __shared__ int s[256];
  int tid = threadIdx.x;
  int i = blockIdx.x * 256 + tid;
  int v = (i < N_NODES) ? deg[i] : 0;
  s[tid] = v;
  __syncthreads();
  for (int off = 1; off < 256; off <<= 1) {
    int t = (tid >= off) ? s[tid - off] : 0;
    __syncthreads();
    s[tid] += t;
    __syncthreads();
  }
  if (i < N_NODES) offsets[i] = s[tid] - v;       // exclusive within block
  if (tid == 255) blockSums[blockIdx.x] = s[255];
}

__global__ __launch_bounds__(512) void scan2_kernel(int* __restrict__ blockSums) {
  __shared__ int s[512];
  int tid = threadIdx.x;
  int v = (tid < SCAN_BLOCKS) ? blockSums[tid] : 0;
  s[tid] = v;
  __syncthreads();
  for (int off = 1; off < 512; off <<= 1) {
    int t = (tid >= off) ? s[tid - off] : 0;
    __syncthreads();
    s[tid] += t;
    __syncthreads();
  }
  if (tid < SCAN_BLOCKS) blockSums[tid] = s[tid] - v;
}

__global__ __launch_bounds__(256) void scan3_kernel(
    int* __restrict__ offsets, const int* __restrict__ blockSums,
    int* __restrict__ cursor) {
  int i = blockIdx.x * 256 + threadIdx.x;
  if (i < N_NODES) {
    int o = offsets[i] + blockSums[blockIdx.x];
    offsets[i] = o;
    cursor[i] = o;
  }
  if (blockIdx.x == 0 && threadIdx.x == 0) offsets[N_NODES] = N_EDGES;
}

// csr[p] = src node id; csr2[p] = x[src] (emb row for layer-1 gather)
__global__ void fill_kernel(const int* __restrict__ ei, const int* __restrict__ x,
                            int* __restrict__ cursor,
                            int* __restrict__ csr, int* __restrict__ csr2) {
  int e = blockIdx.x * 256 + threadIdx.x;
  if (e < N_EDGES) {
    int s = ei[e];
    int d = ei[N_EDGES + e];
    int p = atomicAdd(&cursor[d], 1);
    csr[p] = s;
    csr2[p] = x[s];
  }
}

// ---------------- aggregation: agg[i,:] = sum_{j->i} feat[srcidx[j],:] ----------------
__global__ __launch_bounds__(256) void agg_kernel(
    const float* __restrict__ feat, const int* __restrict__ srcidx,
    const int* __restrict__ offs, const float* __restrict__ zrow,
    float* __restrict__ aggout) {
  int sub = threadIdx.x >> 5;
  int fq  = threadIdx.x & 31;
  int node = blockIdx.x * 8 + sub;
  const float4* __restrict__ f4 = (const float4*)feat;
  const float4* __restrict__ z4 = (const float4*)zrow;

  float4 acc0 = make_float4(0.f, 0.f, 0.f, 0.f);
  float4 acc1 = make_float4(0.f, 0.f, 0.f, 0.f);
  int s = offs[node], e = offs[node + 1];
  for (int p = s; p < e; p += 8) {
    const float4* rp[8];
#pragma unroll
    for (int u = 0; u < 8; ++u) {
      int iu = srcidx[p + u];                       // safe: padded by 8
      rp[u] = (p + u < e) ? (f4 + (size_t)iu * 32) : z4;
    }
    float4 v0 = rp[0][fq];
    float4 v1 = rp[1][fq];
    float4 v2 = rp[2][fq];
    float4 v3 = rp[3][fq];
    float4 v4 = rp[4][fq];
    float4 v5 = rp[5][fq];
    float4 v6 = rp[6][fq];
    float4 v7 = rp[7][fq];
    acc0.x += v0.x + v2.x + v4.x + v6.x;
    acc0.y += v0.y + v2.y + v4.y + v6.y;
    acc0.z += v0.z + v2.z + v4.z + v6.z;
    acc0.w += v0.w + v2.w + v4.w + v6.w;
    acc1.x += v1.x + v3.x + v5.x + v7.x;
    acc1.y += v1.y + v3.y + v5.y + v7.y;
    acc1.z += v1.z + v3.z + v5.z + v7.z;
    acc1.w += v1.w + v3.w + v5.w + v7.w;
  }
  float4 a = make_float4(acc0.x + acc1.x, acc0.y + acc1.y,
                         acc0.z + acc1.z, acc0.w + acc1.w);
  ((float4*)aggout)[(size_t)node * 32 + fq] = a;
}

// ---------------- GEMM: hout = relu([agg | h] @ [wrel; wroot] + b) ----------------
// 128 nodes x 128 cols per block, 256 threads, 8x8 register tile.
// XOR-swizzled LDS (pitch 32, no pad), all inner reads are ds_read_b128:
//   A_s: element (n,k)  at n*32 + (k ^ 4*((n>>3)&7))   [k-quad granular XOR]
//   W_s: element (c,k)  at c*32 + (k ^ 4*((c>>3)&7))   [stored TRANSPOSED]
// Thread (tr,tc): rows 8tr+i, cols 8tc+j (both consecutive-8).
// In-place hsrc==hout safe: block reads only its own rows, stores at end.
__global__ __launch_bounds__(256) void gemm_kernel(
    const float* __restrict__ agg, const float* __restrict__ hsrc,
    const int* __restrict__ hidx,
    const float* __restrict__ wrel, const float* __restrict__ wroot,
    const float* __restrict__ bias, float* __restrict__ hout) {
  __shared__ float A_s[128 * 32];
  __shared__ float W_s[128 * 32];
  int tid = threadIdx.x;
  int nodeBase = blockIdx.x * 128;
  int tc = tid & 15, tr = tid >> 4;

  // ---- staging descriptors ----
  // A: f = tid + 256*i -> n = f>>3 (0..127), q = f&7 (float4 within 32-k slab)
  int a_dst[4];
  const float* aggp[4];
  const float* hp[4];
#pragma unroll
  for (int i = 0; i < 4; ++i) {
    int f = tid + 256 * i;
    int n = f >> 3;
    int q = f & 7;
    a_dst[i] = n * 32 + ((q * 4) ^ (4 * ((n >> 3) & 7)));
    int gn = nodeBase + n;
    if (gn > N_NODES - 1) gn = N_NODES - 1;
    aggp[i] = agg + (size_t)gn * FDIM + q * 4;
    int hr = hidx ? hidx[gn] : gn;
    hp[i] = hsrc + (size_t)hr * FDIM + q * 4;
  }
  // W: f = tid + 256*i -> wk = f>>5 (k 0..31), wq = f&31 (col quad 0..31)
  int wk[4], wq[4];
#pragma unroll
  for (int i = 0; i < 4; ++i) {
    int f = tid + 256 * i;
    wk[i] = f >> 5;
    wq[i] = f & 31;
  }

  float acc[8][8];
  {
    float4 b0 = *(const float4*)&bias[tc * 8];
    float4 b1 = *(const float4*)&bias[tc * 8 + 4];
    float bb[8] = {b0.x, b0.y, b0.z, b0.w, b1.x, b1.y, b1.z, b1.w};
#pragma unroll
    for (int i = 0; i < 8; ++i)
#pragma unroll
      for (int j = 0; j < 8; ++j) acc[i][j] = bb[j];
  }

  const int asw = 4 * (tr & 7);
  const int wsw = 4 * (tc & 7);

#pragma unroll 1
  for (int t = 0; t < 8; ++t) {          // 8 k-tiles of 32 over [agg | h]
    __syncthreads();
    // stage A slab
#pragma unroll
    for (int i = 0; i < 4; ++i) {
      const float* src = (t < 4) ? (aggp[i] + t * 32) : (hp[i] + (t - 4) * 32);
      float4 v = *(const float4*)src;
      float* d = &A_s[a_dst[i]];
      d[0] = v.x; d[1] = v.y; d[2] = v.z; d[3] = v.w;
    }
    // stage W slab (transpose into W_s)
    const float* W = (t < 4) ? (wrel + (size_t)(t * 32) * FDIM)
                             : (wroot + (size_t)((t - 4) * 32) * FDIM);
#pragma unroll
    for (int i = 0; i < 4; ++i) {
      float4 v = *(const float4*)(W + (size_t)wk[i] * FDIM + wq[i] * 4);
      int c0 = wq[i] * 4;
      W_s[(c0 + 0) * 32 + (wk[i] ^ (4 * (((c0 + 0) >> 3) & 7)))] = v.x;
      W_s[(c0 + 1) * 32 + (wk[i] ^ (4 * (((c0 + 1) >> 3) & 7)))] = v.y;
      W_s[(c0 + 2) * 32 + (wk[i] ^ (4 * (((c0 + 2) >> 3) & 7)))] = v.z;
      W_s[(c0 + 3) * 32 + (wk[i] ^ (4 * (((c0 + 3) >> 3) & 7)))] = v.w;
    }
    __syncthreads();

#pragma unroll
    for (int k0 = 0; k0 < 32; k0 += 4) {
      float4 a4[8], w4[8];
#pragma unroll
      for (int i = 0; i < 8; ++i)
        a4[i] = *(const float4*)&A_s[(8 * tr + i) * 32 + (k0 ^ asw)];
#pragma unroll
      for (int j = 0; j < 8; ++j)
        w4[j] = *(const float4*)&W_s[(8 * tc + j) * 32 + (k0 ^ wsw)];
#pragma unroll
      for (int i = 0; i < 8; ++i)
#pragma unroll
        for (int j = 0; j < 8; ++j)
          acc[i][j] += a4[i].x * w4[j].x + a4[i].y * w4[j].y +
                       a4[i].z * w4[j].z + a4[i].w * w4[j].w;
    }
  }

  // epilogue: relu + vectorized store (cols 8tc..8tc+7 consecutive)
#pragma unroll
  for (int i = 0; i < 8; ++i) {
    int n = nodeBase + tr * 8 + i;
    if (n < N_NODES) {
      float* o = hout + (size_t)n * FDIM + tc * 8;
      float4 v0, v1;
      v0.x = fmaxf(acc[i][0], 0.f); v0.y = fmaxf(acc[i][1], 0.f);
      v0.z = fmaxf(acc[i][2], 0.f); v0.w = fmaxf(acc[i][3], 0.f);
      v1.x = fmaxf(acc[i][4], 0.f); v1.y = fmaxf(acc[i][5], 0.f);
      v1.z = fmaxf(acc[i][6], 0.f); v1.w = fmaxf(acc[i][7], 0.f);
      *(float4*)o = v0;
      *(float4*)(o + 4) = v1;
    }
  }
}

// ---------------- per-graph segment boundaries (batch is sorted) ----------------
__global__ void find_starts_kernel(const int* __restrict__ batch,
                                   int* __restrict__ start) {
  int i = blockIdx.x * 256 + threadIdx.x;
  if (i >= N_NODES) return;
  int b  = batch[i];
  int bp = (i == 0) ? -1 : batch[i - 1];
  for (int g = bp + 1; g <= b; ++g) start[g] = i;
  if (i == N_NODES - 1) {
    for (int g = b + 1; g <= N_GRAPHS; ++g) start[g] = N_NODES;
  }
}

// ---------------- pooling: max & sum per graph ----------------
__global__ __launch_bounds__(128) void pool_kernel(
    const float* __restrict__ h2, const int* __restrict__ start,
    float* __restrict__ pool) {
  int g = blockIdx.x >> 3;
  int c = blockIdx.x & 7;
  int f = threadIdx.x;
  int s = start[g], e = start[g + 1];
  int len = e - s;
  int lo = s + (int)(((long long)len * c) >> 3);
  int hi = s + (int)(((long long)len * (c + 1)) >> 3);
  float mx = 0.f, sm = 0.f;
  for (int n = lo; n < hi; ++n) {
    float v = h2[(size_t)n * FDIM + f];
    mx = fmaxf(mx, v);
    sm += v;
  }
  atomicMax((unsigned int*)&pool[g * 256 + f], __float_as_uint(mx));
  atomicAdd(&pool[g * 256 + 128 + f], sm);
}

__global__ void pool_fin_kernel(float* __restrict__ pool,
                                const int* __restrict__ start) {
  int gid = blockIdx.x * 256 + threadIdx.x;   // 8192
  int g = gid >> 7, f = gid & 127;
  int cnt = start[g + 1] - start[g];
  float c = (float)(cnt > 1 ? cnt : 1);
  pool[g * 256 + 128 + f] /= c;
}

// ---------------- MLP head ----------------
__global__ void head1_kernel(const float* __restrict__ pool,
                             const float* __restrict__ lw1,
                             const float* __restrict__ lb1,
                             float* __restrict__ t1) {
  int gid = blockIdx.x * 256 + threadIdx.x;   // 8192
  int r = gid >> 7, c = gid & 127;
  float acc = lb1[c];
  for (int k = 0; k < 256; ++k) acc += pool[r * 256 + k] * lw1[k * 128 + c];
  t1[gid] = fmaxf(acc, 0.f);
}

__global__ void head2_kernel(const float* __restrict__ t1,
                             const float* __restrict__ lw2,
                             const float* __restrict__ lb2,
                             float* __restrict__ t2) {
  int gid = blockIdx.x * 256 + threadIdx.x;   // 4096
  int r = gid >> 6, c = gid & 63;
  float acc = lb2[c];
  for (int k = 0; k < 128; ++k) acc += t1[r * 128 + k] * lw2[k * 64 + c];
  t2[gid] = fmaxf(acc, 0.f);
}

__global__ __launch_bounds__(256) void head3_kernel(
    const float* __restrict__ t2, const float* __restrict__ lw3,
    const float* __restrict__ lb3, float* __restrict__ out) {
  __shared__ float lg[N_GRAPHS * N_LABELS];
  __shared__ float col[N_LABELS];
  int tid = threadIdx.x;
  for (int o = tid; o < N_GRAPHS * N_LABELS; o += 256) {
    int r = o / N_LABELS, c = o - r * N_LABELS;
    float acc = lb3[c];
    for (int k = 0; k < 64; ++k) acc += t2[r * 64 + k] * lw3[k * N_LABELS + c];
    lg[o] = acc;
  }
  __syncthreads();
  if (tid < N_LABELS) {
    float m = -1e30f;
    for (int r = 0; r < N_GRAPHS; ++r) m = fmaxf(m, lg[r * N_LABELS + tid]);
    float s = 0.f;
    for (int r = 0; r < N_GRAPHS; ++r) s += expf(lg[r * N_LABELS + tid] - m);
    col[tid] = m + logf(s);
  }
  __syncthreads();
  for (int o = tid; o < N_GRAPHS * N_LABELS; o += 256) {
    int c = o % N_LABELS;
    out[o] = lg[o] - col[c];
  }
}

// ---------------- launch ----------------
extern "C" void kernel_launch(void* const* d_in, const int* in_sizes, int n_in,
                              void* d_out, int out_size, void* d_ws, size_t ws_size,
                              hipStream_t stream) {
  const int*   x     = (const int*)  d_in[0];
  const int*   ei    = (const int*)  d_in[1];
  const int*   batch = (const int*)  d_in[2];
  const float* emb   = (const float*)d_in[3];
  const float* w1rel = (const float*)d_in[4];
  const float* w1rt  = (const float*)d_in[5];
  const float* b1    = (const float*)d_in[6];
  const float* w2rel = (const float*)d_in[7];
  const float* w2rt  = (const float*)d_in[8];
  const float* b2    = (const float*)d_in[9];
  const float* lw1   = (const float*)d_in[10];
  const float* lb1   = (const float*)d_in[11];
  const float* lw2   = (const float*)d_in[12];
  const float* lb2   = (const float*)d_in[13];
  const float* lw3   = (const float*)d_in[14];
  const float* lb3   = (const float*)d_in[15];
  float* out = (float*)d_out;

  char* ws = (char*)d_ws;
  const size_t HB   = 51200000;   // N_NODES*FDIM*4
  const size_t OFFB = 400128;     // (N_NODES+1) ints, rounded
  const size_t CSRB = 6400128;    // (N_EDGES+8) ints, rounded
  float* hB      = (float*)(ws);
  float* aggbuf  = (float*)(ws + HB);
  int*   deg     = (int*)  (ws + 2 * HB);
  int*   offsets = (int*)  (ws + 2 * HB + OFFB);
  int*   cursor  = (int*)  (ws + 2 * HB + 2 * OFFB);
  int*   bsum    = (int*)  (ws + 2 * HB + 3 * OFFB);
  int*   csr     = (int*)  (ws + 2 * HB + 3 * OFFB + 2048);
  int*   csr2    = (int*)  (ws + 2 * HB + 3 * OFFB + 2048 + CSRB);
  int*   start   = (int*)  (ws + 2 * HB + 3 * OFFB + 2048 + 2 * CSRB);
  float* zrow    = (float*)(ws + 2 * HB + 3 * OFFB + 2048 + 2 * CSRB + 512);
  float* pool    = (float*)(ws + 2 * HB + 3 * OFFB + 2048 + 2 * CSRB + 512 + 1024);
  float* t1      = (float*)(ws + 2 * HB + 3 * OFFB + 2048 + 2 * CSRB + 512 + 1024 + 65536);
  float* t2      = (float*)(ws + 2 * HB + 3 * OFFB + 2048 + 2 * CSRB + 512 + 1024 + 65536 + 32768);

  init_kernel<<<SCAN_BLOCKS, 256, 0, stream>>>(deg, pool, zrow, csr, csr2);

  count_kernel<<<(N_EDGES + 255) / 256, 256, 0, stream>>>(ei, deg);
  scan1_kernel<<<SCAN_BLOCKS, 256, 0, stream>>>(deg, offsets, bsum);
  scan2_kernel<<<1, 512, 0, stream>>>(bsum);
  scan3_kernel<<<SCAN_BLOCKS, 256, 0, stream>>>(offsets, bsum, cursor);
  fill_kernel<<<(N_EDGES + 255) / 256, 256, 0, stream>>>(ei, x, cursor, csr, csr2);

  // layer 1: aggregate emb rows via csr2 = x[src]; h-term gathered from emb via x
  agg_kernel<<<N_NODES / 8, 256, 0, stream>>>(emb, csr2, offsets, zrow, aggbuf);
  gemm_kernel<<<(N_NODES + 127) / 128, 256, 0, stream>>>(aggbuf, emb, x,
                                                         w1rel, w1rt, b1, hB);

  // layer 2: aggregate hB rows via csr; in-place gemm on hB
  agg_kernel<<<N_NODES / 8, 256, 0, stream>>>(hB, csr, offsets, zrow, aggbuf);
  gemm_kernel<<<(N_NODES + 127) / 128, 256, 0, stream>>>(aggbuf, hB,
                                                         (const int*)nullptr,
                                                         w2rel, w2rt, b2, hB);

  find_starts_kernel<<<SCAN_BLOCKS, 256, 0, stream>>>(batch, start);
  pool_kernel<<<N_GRAPHS * 8, 128, 0, stream>>>(hB, start, pool);
  pool_fin_kernel<<<32, 256, 0, stream>>>(pool, start);

  head1_kernel<<<32, 256, 0, stream>>>(pool, lw1, lb1, t1);
  head2_kernel<<<16, 256, 0, stream>>>(t1, lw2, lb2, t2);
  head3_kernel<<<1, 256, 0, stream>>>(t2, lw3, lb3, out);
}

// Round 6
// 752.298 us; speedup vs baseline: 2.8267x; 2.8267x over previous
//
#include <hip/hip_runtime.h>
#include <hip/hip_bf16.h>

#define N_NODES   100000
#define N_EDGES   1600000
#define N_GRAPHS  64
#define FDIM      128
#define N_LABELS  20
#define SCAN_BLOCKS 391   // ceil(N_NODES/256)

// ---------------- init: zero deg, pool, zrow, csr pads ----------------
__global__ __launch_bounds__(256) void init_kernel(
    int* __restrict__ deg, float* __restrict__ pool, float* __restrict__ zrow,
    int* __restrict__ csr, int* __restrict__ csr2) {
  int i = blockIdx.x * 256 + threadIdx.x;
  if (i < N_NODES) deg[i] = 0;
  if (i < N_GRAPHS * 256) pool[i] = 0.f;
  if (i < FDIM) zrow[i] = 0.f;
  if (i < 8) { csr[N_EDGES + i] = 0; csr2[N_EDGES + i] = 0; }
}

// ---------------- CSR build ----------------
__global__ void count_kernel(const int* __restrict__ ei, int* __restrict__ deg) {
  int e = blockIdx.x * 256 + threadIdx.x;
  if (e < N_EDGES) atomicAdd(&deg[ei[N_EDGES + e]], 1);
}

__global__ __launch_bounds__(256) void scan1_kernel(
    const int* __restrict__ deg, int* __restrict__ offsets,
    int* __restrict__ blockSums) {
  __shared__ int s[256];
  int tid = threadIdx.x;
  int i = blockIdx.x * 256 + tid;
  int v = (i < N_NODES) ? deg[i] : 0;
  s[tid] = v;
  __syncthreads();
  for (int off = 1; off < 256; off <<= 1) {
    int t = (tid >= off) ? s[tid - off] : 0;
    __syncthreads();
    s[tid] += t;
    __syncthreads();
  }
  if (i < N_NODES) offsets[i] = s[tid] - v;       // exclusive within block
  if (tid == 255) blockSums[blockIdx.x] = s[255];
}

__global__ __launch_bounds__(512) void scan2_kernel(int* __restrict__ blockSums) {
  __shared__ int s[512];
  int tid = threadIdx.x;
  int v = (tid < SCAN_BLOCKS) ? blockSums[tid] : 0;
  s[tid] = v;
  __syncthreads();
  for (int off = 1; off < 512; off <<= 1) {
    int t = (tid >= off) ? s[tid - off] : 0;
    __syncthreads();
    s[tid] += t;
    __syncthreads();
  }
  if (tid < SCAN_BLOCKS) blockSums[tid] = s[tid] - v;
}

__global__ __launch_bounds__(256) void scan3_kernel(
    int* __restrict__ offsets, const int* __restrict__ blockSums,
    int* __restrict__ cursor) {
  int i = blockIdx.x * 256 + threadIdx.x;
  if (i < N_NODES) {
    int o = offsets[i] + blockSums[blockIdx.x];
    offsets[i] = o;
    cursor[i] = o;
  }
  if (blockIdx.x == 0 && threadIdx.x == 0) offsets[N_NODES] = N_EDGES;
}

// csr[p] = src node id; csr2[p] = x[src] (emb row for layer-1 gather)
__global__ void fill_kernel(const int* __restrict__ ei, const int* __restrict__ x,
                            int* __restrict__ cursor,
                            int* __restrict__ csr, int* __restrict__ csr2) {
  int e = blockIdx.x * 256 + threadIdx.x;
  if (e < N_EDGES) {
    int s = ei[e];
    int d = ei[N_EDGES + e];
    int p = atomicAdd(&cursor[d], 1);
    csr[p] = s;
    csr2[p] = x[s];
  }
}

// ---------------- aggregation: agg[i,:] = sum_{j->i} feat[srcidx[j],:] ----------------
__global__ __launch_bounds__(256) void agg_kernel(
    const float* __restrict__ feat, const int* __restrict__ srcidx,
    const int* __restrict__ offs, const float* __restrict__ zrow,
    float* __restrict__ aggout) {
  int sub = threadIdx.x >> 5;
  int fq  = threadIdx.x & 31;
  int node = blockIdx.x * 8 + sub;
  const float4* __restrict__ f4 = (const float4*)feat;
  const float4* __restrict__ z4 = (const float4*)zrow;

  float4 acc0 = make_float4(0.f, 0.f, 0.f, 0.f);
  float4 acc1 = make_float4(0.f, 0.f, 0.f, 0.f);
  int s = offs[node], e = offs[node + 1];
  for (int p = s; p < e; p += 8) {
    const float4* rp[8];
#pragma unroll
    for (int u = 0; u < 8; ++u) {
      int iu = srcidx[p + u];                       // safe: padded by 8
      rp[u] = (p + u < e) ? (f4 + (size_t)iu * 32) : z4;
    }
    float4 v0 = rp[0][fq];
    float4 v1 = rp[1][fq];
    float4 v2 = rp[2][fq];
    float4 v3 = rp[3][fq];
    float4 v4 = rp[4][fq];
    float4 v5 = rp[5][fq];
    float4 v6 = rp[6][fq];
    float4 v7 = rp[7][fq];
    acc0.x += v0.x + v2.x + v4.x + v6.x;
    acc0.y += v0.y + v2.y + v4.y + v6.y;
    acc0.z += v0.z + v2.z + v4.z + v6.z;
    acc0.w += v0.w + v2.w + v4.w + v6.w;
    acc1.x += v1.x + v3.x + v5.x + v7.x;
    acc1.y += v1.y + v3.y + v5.y + v7.y;
    acc1.z += v1.z + v3.z + v5.z + v7.z;
    acc1.w += v1.w + v3.w + v5.w + v7.w;
  }
  float4 a = make_float4(acc0.x + acc1.x, acc0.y + acc1.y,
                         acc0.z + acc1.z, acc0.w + acc1.w);
  ((float4*)aggout)[(size_t)node * 32 + fq] = a;
}

// ---------------- GEMM: hout = relu([agg | h] @ [wrel; wroot] + b) ----------------
// 128 nodes x 128 cols per block, 256 threads, 8x8 register tile.
// A_s: pitch 32, element (n,k) at n*32 + (k ^ 4*((n>>3)&7)) -> b128 reads,
//      4 tr-groups hit 4 distinct bank-quads (conflict-free).
// W_s: row-major [32][128], direct b128 copy staging (no transpose).
//      Thread's 8 cols = {4tc..4tc+3, 64+4tc..67+4tc}: per-k 2 b128 reads at
//      quads tc%8 -> 2 addresses/quad = floor.
// Register discipline: k0-loop unroll 1; live = acc(64)+a4(32)+w(8) ~ 130 VGPR.
__global__ __launch_bounds__(256) void gemm_kernel(
    const float* __restrict__ agg, const float* __restrict__ hsrc,
    const int* __restrict__ hidx,
    const float* __restrict__ wrel, const float* __restrict__ wroot,
    const float* __restrict__ bias, float* __restrict__ hout) {
  __shared__ float A_s[128 * 32];
  __shared__ float W_s[32 * 128];
  int tid = threadIdx.x;
  int nodeBase = blockIdx.x * 128;
  int tc = tid & 15, tr = tid >> 4;

  // staging descriptors: A slot i covers (n = (tid+256i)>>3, q = (tid+256i)&7)
  int a_gn[4], a_hr[4], a_q[4], a_lds[4];
#pragma unroll
  for (int i = 0; i < 4; ++i) {
    int f = tid + 256 * i;
    int n = f >> 3, q = f & 7;
    int gn = nodeBase + n;
    if (gn > N_NODES - 1) gn = N_NODES - 1;
    a_gn[i] = gn;
    a_hr[i] = hidx ? hidx[gn] : gn;
    a_q[i] = q;
    a_lds[i] = n * 32 + ((q * 4) ^ (4 * ((n >> 3) & 7)));
  }

  float acc[8][8];
  {
    float4 b0 = *(const float4*)&bias[4 * tc];
    float4 b1 = *(const float4*)&bias[64 + 4 * tc];
#pragma unroll
    for (int i = 0; i < 8; ++i) {
      acc[i][0] = b0.x; acc[i][1] = b0.y; acc[i][2] = b0.z; acc[i][3] = b0.w;
      acc[i][4] = b1.x; acc[i][5] = b1.y; acc[i][6] = b1.z; acc[i][7] = b1.w;
    }
  }

  const int kx_base = 4 * (tr & 7);   // A-row XOR (uniform over thread's 8 rows)

#pragma unroll 1
  for (int t = 0; t < 8; ++t) {       // 8 k-tiles of 32 over [agg | h]
    __syncthreads();
    // stage A slab: 1 global b128 + 1 LDS b128 per slot
#pragma unroll
    for (int i = 0; i < 4; ++i) {
      const float* src = (t < 4)
          ? (agg  + (size_t)a_gn[i] * FDIM + t * 32 + a_q[i] * 4)
          : (hsrc + (size_t)a_hr[i] * FDIM + (t - 4) * 32 + a_q[i] * 4);
      *(float4*)&A_s[a_lds[i]] = *(const float4*)src;
    }
    // stage W slab: direct row-major b128 copy
    const float* W = (t < 4) ? (wrel + (size_t)(t * 32) * FDIM)
                             : (wroot + (size_t)((t - 4) * 32) * FDIM);
#pragma unroll
    for (int i = 0; i < 4; ++i) {
      int f = tid + 256 * i;
      int wk = f >> 5, wq = f & 31;
      *(float4*)&W_s[wk * 128 + wq * 4] =
          *(const float4*)(W + (size_t)wk * FDIM + wq * 4);
    }
    __syncthreads();

#pragma unroll 1
    for (int k0 = 0; k0 < 32; k0 += 4) {
      float4 a4[8];
      int kx = k0 ^ kx_base;
#pragma unroll
      for (int i = 0; i < 8; ++i)
        a4[i] = *(const float4*)&A_s[(8 * tr + i) * 32 + kx];
#pragma unroll
      for (int kk = 0; kk < 4; ++kk) {
        float4 w0 = *(const float4*)&W_s[(k0 + kk) * 128 + 4 * tc];
        float4 w1 = *(const float4*)&W_s[(k0 + kk) * 128 + 64 + 4 * tc];
#pragma unroll
        for (int i = 0; i < 8; ++i) {
          float a = (kk == 0) ? a4[i].x : (kk == 1) ? a4[i].y
                  : (kk == 2) ? a4[i].z : a4[i].w;
          acc[i][0] += a * w0.x; acc[i][1] += a * w0.y;
          acc[i][2] += a * w0.z; acc[i][3] += a * w0.w;
          acc[i][4] += a * w1.x; acc[i][5] += a * w1.y;
          acc[i][6] += a * w1.z; acc[i][7] += a * w1.w;
        }
      }
    }
  }

  // epilogue: relu + two b128 stores per row (cols 4tc.. and 64+4tc..)
#pragma unroll
  for (int i = 0; i < 8; ++i) {
    int n = nodeBase + tr * 8 + i;
    if (n < N_NODES) {
      float* o = hout + (size_t)n * FDIM;
      float4 v0, v1;
      v0.x = fmaxf(acc[i][0], 0.f); v0.y = fmaxf(acc[i][1], 0.f);
      v0.z = fmaxf(acc[i][2], 0.f); v0.w = fmaxf(acc[i][3], 0.f);
      v1.x = fmaxf(acc[i][4], 0.f); v1.y = fmaxf(acc[i][5], 0.f);
      v1.z = fmaxf(acc[i][6], 0.f); v1.w = fmaxf(acc[i][7], 0.f);
      *(float4*)(o + 4 * tc) = v0;
      *(float4*)(o + 64 + 4 * tc) = v1;
    }
  }
}

// ---------------- per-graph segment boundaries (batch is sorted) ----------------
__global__ void find_starts_kernel(const int* __restrict__ batch,
                                   int* __restrict__ start) {
  int i = blockIdx.x * 256 + threadIdx.x;
  if (i >= N_NODES) return;
  int b  = batch[i];
  int bp = (i == 0) ? -1 : batch[i - 1];
  for (int g = bp + 1; g <= b; ++g) start[g] = i;
  if (i == N_NODES - 1) {
    for (int g = b + 1; g <= N_GRAPHS; ++g) start[g] = N_NODES;
  }
}

// ---------------- pooling: max & sum per graph ----------------
__global__ __launch_bounds__(128) void pool_kernel(
    const float* __restrict__ h2, const int* __restrict__ start,
    float* __restrict__ pool) {
  int g = blockIdx.x >> 3;
  int c = blockIdx.x & 7;
  int f = threadIdx.x;
  int s = start[g], e = start[g + 1];
  int len = e - s;
  int lo = s + (int)(((long long)len * c) >> 3);
  int hi = s + (int)(((long long)len * (c + 1)) >> 3);
  float mx = 0.f, sm = 0.f;
  for (int n = lo; n < hi; ++n) {
    float v = h2[(size_t)n * FDIM + f];
    mx = fmaxf(mx, v);
    sm += v;
  }
  atomicMax((unsigned int*)&pool[g * 256 + f], __float_as_uint(mx));
  atomicAdd(&pool[g * 256 + 128 + f], sm);
}

__global__ void pool_fin_kernel(float* __restrict__ pool,
                                const int* __restrict__ start) {
  int gid = blockIdx.x * 256 + threadIdx.x;   // 8192
  int g = gid >> 7, f = gid & 127;
  int cnt = start[g + 1] - start[g];
  float c = (float)(cnt > 1 ? cnt : 1);
  pool[g * 256 + 128 + f] /= c;
}

// ---------------- MLP head ----------------
__global__ void head1_kernel(const float* __restrict__ pool,
                             const float* __restrict__ lw1,
                             const float* __restrict__ lb1,
                             float* __restrict__ t1) {
  int gid = blockIdx.x * 256 + threadIdx.x;   // 8192
  int r = gid >> 7, c = gid & 127;
  float acc = lb1[c];
  for (int k = 0; k < 256; ++k) acc += pool[r * 256 + k] * lw1[k * 128 + c];
  t1[gid] = fmaxf(acc, 0.f);
}

__global__ void head2_kernel(const float* __restrict__ t1,
                             const float* __restrict__ lw2,
                             const float* __restrict__ lb2,
                             float* __restrict__ t2) {
  int gid = blockIdx.x * 256 + threadIdx.x;   // 4096
  int r = gid >> 6, c = gid & 63;
  float acc = lb2[c];
  for (int k = 0; k < 128; ++k) acc += t1[r * 128 + k] * lw2[k * 64 + c];
  t2[gid] = fmaxf(acc, 0.f);
}

__global__ __launch_bounds__(256) void head3_kernel(
    const float* __restrict__ t2, const float* __restrict__ lw3,
    const float* __restrict__ lb3, float* __restrict__ out) {
  __shared__ float lg[N_GRAPHS * N_LABELS];
  __shared__ float col[N_LABELS];
  int tid = threadIdx.x;
  for (int o = tid; o < N_GRAPHS * N_LABELS; o += 256) {
    int r = o / N_LABELS, c = o - r * N_LABELS;
    float acc = lb3[c];
    for (int k = 0; k < 64; ++k) acc += t2[r * 64 + k] * lw3[k * N_LABELS + c];
    lg[o] = acc;
  }
  __syncthreads();
  if (tid < N_LABELS) {
    float m = -1e30f;
    for (int r = 0; r < N_GRAPHS; ++r) m = fmaxf(m, lg[r * N_LABELS + tid]);
    float s = 0.f;
    for (int r = 0; r < N_GRAPHS; ++r) s += expf(lg[r * N_LABELS + tid] - m);
    col[tid] = m + logf(s);
  }
  __syncthreads();
  for (int o = tid; o < N_GRAPHS * N_LABELS; o += 256) {
    int c = o % N_LABELS;
    out[o] = lg[o] - col[c];
  }
}

// ---------------- launch ----------------
extern "C" void kernel_launch(void* const* d_in, const int* in_sizes, int n_in,
                              void* d_out, int out_size, void* d_ws, size_t ws_size,
                              hipStream_t stream) {
  const int*   x     = (const int*)  d_in[0];
  const int*   ei    = (const int*)  d_in[1];
  const int*   batch = (const int*)  d_in[2];
  const float* emb   = (const float*)d_in[3];
  const float* w1rel = (const float*)d_in[4];
  const float* w1rt  = (const float*)d_in[5];
  const float* b1    = (const float*)d_in[6];
  const float* w2rel = (const float*)d_in[7];
  const float* w2rt  = (const float*)d_in[8];
  const float* b2    = (const float*)d_in[9];
  const float* lw1   = (const float*)d_in[10];
  const float* lb1   = (const float*)d_in[11];
  const float* lw2   = (const float*)d_in[12];
  const float* lb2   = (const float*)d_in[13];
  const float* lw3   = (const float*)d_in[14];
  const float* lb3   = (const float*)d_in[15];
  float* out = (float*)d_out;

  char* ws = (char*)d_ws;
  const size_t HB   = 51200000;   // N_NODES*FDIM*4
  const size_t OFFB = 400128;     // (N_NODES+1) ints, rounded
  const size_t CSRB = 6400128;    // (N_EDGES+8) ints, rounded
  float* hB      = (float*)(ws);
  float* aggbuf  = (float*)(ws + HB);
  int*   deg     = (int*)  (ws + 2 * HB);
  int*   offsets = (int*)  (ws + 2 * HB + OFFB);
  int*   cursor  = (int*)  (ws + 2 * HB + 2 * OFFB);
  int*   bsum    = (int*)  (ws + 2 * HB + 3 * OFFB);
  int*   csr     = (int*)  (ws + 2 * HB + 3 * OFFB + 2048);
  int*   csr2    = (int*)  (ws + 2 * HB + 3 * OFFB + 2048 + CSRB);
  int*   start   = (int*)  (ws + 2 * HB + 3 * OFFB + 2048 + 2 * CSRB);
  float* zrow    = (float*)(ws + 2 * HB + 3 * OFFB + 2048 + 2 * CSRB + 512);
  float* pool    = (float*)(ws + 2 * HB + 3 * OFFB + 2048 + 2 * CSRB + 512 + 1024);
  float* t1      = (float*)(ws + 2 * HB + 3 * OFFB + 2048 + 2 * CSRB + 512 + 1024 + 65536);
  float* t2      = (float*)(ws + 2 * HB + 3 * OFFB + 2048 + 2 * CSRB + 512 + 1024 + 65536 + 32768);

  init_kernel<<<SCAN_BLOCKS, 256, 0, stream>>>(deg, pool, zrow, csr, csr2);

  count_kernel<<<(N_EDGES + 255) / 256, 256, 0, stream>>>(ei, deg);
  scan1_kernel<<<SCAN_BLOCKS, 256, 0, stream>>>(deg, offsets, bsum);
  scan2_kernel<<<1, 512, 0, stream>>>(bsum);
  scan3_kernel<<<SCAN_BLOCKS, 256, 0, stream>>>(offsets, bsum, cursor);
  fill_kernel<<<(N_EDGES + 255) / 256, 256, 0, stream>>>(ei, x, cursor, csr, csr2);

  // layer 1: aggregate emb rows via csr2 = x[src]; h-term gathered from emb via x
  agg_kernel<<<N_NODES / 8, 256, 0, stream>>>(emb, csr2, offsets, zrow, aggbuf);
  gemm_kernel<<<(N_NODES + 127) / 128, 256, 0, stream>>>(aggbuf, emb, x,
                                                         w1rel, w1rt, b1, hB);

  // layer 2: aggregate hB rows via csr; in-place gemm on hB
  agg_kernel<<<N_NODES / 8, 256, 0, stream>>>(hB, csr, offsets, zrow, aggbuf);
  gemm_kernel<<<(N_NODES + 127) / 128, 256, 0, stream>>>(aggbuf, hB,
                                                         (const int*)nullptr,
                                                         w2rel, w2rt, b2, hB);

  find_starts_kernel<<<SCAN_BLOCKS, 256, 0, stream>>>(batch, start);
  pool_kernel<<<N_GRAPHS * 8, 128, 0, stream>>>(hB, start, pool);
  pool_fin_kernel<<<32, 256, 0, stream>>>(pool, start);

  head1_kernel<<<32, 256, 0, stream>>>(pool, lw1, lb1, t1);
  head2_kernel<<<16, 256, 0, stream>>>(t1, lw2, lb2, t2);
  head3_kernel<<<1, 256, 0, stream>>>(t2, lw3, lb3, out);
}